// Round 1
// baseline (1114.753 us; speedup 1.0000x reference)
//
#include <hip/hip_runtime.h>
#include <stdint.h>

#define SEQ 4096
#define DM  1024
#define NB  4
#define QSCALE 0.06f

typedef __attribute__((ext_vector_type(8))) short short8;
typedef __attribute__((ext_vector_type(4))) float floatx4;

__device__ __forceinline__ unsigned short f2bf(float f) {
  union { float f; unsigned int u; } v; v.f = f;
  unsigned int u = v.u;
  u += 0x7FFFu + ((u >> 16) & 1u);
  return (unsigned short)(u >> 16);
}

__device__ __forceinline__ void async16(const void* g, void* l) {
  __builtin_amdgcn_global_load_lds(
      (const __attribute__((address_space(1))) void*)g,
      (__attribute__((address_space(3))) void*)l, 16, 0, 0);
}

// ---------------- fp32 -> bf16 convert (8 elems/thread) ----------------
__global__ void cvt_bf16(const float* __restrict__ in,
                         unsigned short* __restrict__ out, int n) {
  int i = (blockIdx.x * 256 + threadIdx.x) * 8;
  if (i >= n) return;
  const float4* p = (const float4*)(in + i);
  float4 a = p[0], b = p[1];
  short8 o;
  o[0] = (short)f2bf(a.x); o[1] = (short)f2bf(a.y);
  o[2] = (short)f2bf(a.z); o[3] = (short)f2bf(a.w);
  o[4] = (short)f2bf(b.x); o[5] = (short)f2bf(b.y);
  o[6] = (short)f2bf(b.z); o[7] = (short)f2bf(b.w);
  *(short8*)(out + i) = o;
}

// ---------------- m97-style 128x128 bf16 GEMM, C = A * W^T ----------------
// A: [M x 1024] bf16 row-major.  W: [1024 x 1024] bf16 row-major (K-contig).
template <bool OUT_BF16>
__global__ __launch_bounds__(256) void gemm_bt(
    const unsigned short* __restrict__ A, const unsigned short* __restrict__ W,
    void* __restrict__ Cout, float alpha) {
  __shared__ unsigned short sA[128 * 32];
  __shared__ unsigned short sB[128 * 32];
  const int K = 1024;
  int tid = threadIdx.x;
  int wid = tid >> 6, lane = tid & 63;
  int wr = wid >> 1, wc = wid & 1;
  long rowBase = (long)blockIdx.x * 128;
  int colBase = blockIdx.y * 128;

  floatx4 acc[4][4];
#pragma unroll
  for (int i = 0; i < 4; i++)
#pragma unroll
    for (int j = 0; j < 4; j++) acc[i][j] = (floatx4){0.f, 0.f, 0.f, 0.f};

  int c0 = wid * 64 + lane;
  int c1 = c0 + 256;
  const unsigned short* Ag0 = A + (rowBase + (c0 >> 2)) * K + (c0 & 3) * 8;
  const unsigned short* Ag1 = A + (rowBase + (c1 >> 2)) * K + (c1 & 3) * 8;
  const unsigned short* Bg0 = W + ((long)colBase + (c0 >> 2)) * K + (c0 & 3) * 8;
  const unsigned short* Bg1 = W + ((long)colBase + (c1 >> 2)) * K + (c1 & 3) * 8;
  unsigned short* sA0 = sA + (wid * 64) * 8;
  unsigned short* sA1 = sA + (256 + wid * 64) * 8;
  unsigned short* sB0 = sB + (wid * 64) * 8;
  unsigned short* sB1 = sB + (256 + wid * 64) * 8;

  int aRd = (wr * 64 + (lane & 15)) * 32 + (lane >> 4) * 8;
  int bRd = (wc * 64 + (lane & 15)) * 32 + (lane >> 4) * 8;

  for (int ks = 0; ks < K; ks += 32) {
    async16(Ag0 + ks, sA0);
    async16(Ag1 + ks, sA1);
    async16(Bg0 + ks, sB0);
    async16(Bg1 + ks, sB1);
    __syncthreads();
    short8 af[4], bf[4];
#pragma unroll
    for (int mt = 0; mt < 4; mt++) af[mt] = *(const short8*)(sA + aRd + mt * 512);
#pragma unroll
    for (int nt = 0; nt < 4; nt++) bf[nt] = *(const short8*)(sB + bRd + nt * 512);
#pragma unroll
    for (int mt = 0; mt < 4; mt++)
#pragma unroll
      for (int nt = 0; nt < 4; nt++)
        acc[mt][nt] = __builtin_amdgcn_mfma_f32_16x16x32_bf16(
            af[mt], bf[nt], acc[mt][nt], 0, 0, 0);
    __syncthreads();
  }

  long crow = rowBase + wr * 64 + (lane >> 4) * 4;
  int ccol = colBase + wc * 64 + (lane & 15);
#pragma unroll
  for (int mt = 0; mt < 4; mt++)
#pragma unroll
    for (int nt = 0; nt < 4; nt++)
#pragma unroll
      for (int r = 0; r < 4; r++) {
        float v = acc[mt][nt][r] * alpha;
        long idx = (crow + mt * 16 + r) * 1024 + ccol + nt * 16;
        if (OUT_BF16)
          ((unsigned short*)Cout)[idx] = f2bf(v);
        else
          ((float*)Cout)[idx] = v;
      }
}

// ---------------- V transpose: Vb[b][m][o] -> Vt[b][o][m] (bf16) ----------------
__global__ __launch_bounds__(256) void transpose_v(
    const unsigned short* __restrict__ Vb, unsigned short* __restrict__ Vt) {
  __shared__ unsigned short tile[64][65];
  int b = blockIdx.z;
  int m0 = blockIdx.x * 64, o0 = blockIdx.y * 64;
  int t = threadIdx.x;
  int tm = t >> 6, to = t & 63;
  const unsigned short* src = Vb + ((long)b * SEQ + m0) * 1024 + o0;
#pragma unroll
  for (int i = 0; i < 16; i++) {
    int mm = tm * 16 + i;
    tile[mm][to] = src[(long)mm * 1024 + to];
  }
  __syncthreads();
  unsigned short* dst = Vt + ((long)b * 1024 + o0) * (long)SEQ + m0;
#pragma unroll
  for (int i = 0; i < 16; i++) {
    int oo = tm * 16 + i;
    dst[(long)oo * SEQ + to] = tile[to][oo];
  }
}

// ---------------- banded logits: att[b][n][m] = Q[n].K[m] (band tiles) ----------------
__global__ __launch_bounds__(256, 2) void attn_logits(
    const unsigned short* __restrict__ Qb, const unsigned short* __restrict__ Kb,
    float* __restrict__ att) {
  int b = blockIdx.y;
  int nt = blockIdx.x;  // 16-row tile
  int n0 = nt * 16;
  int wid = threadIdx.x >> 6, lane = threadIdx.x & 63;
  const unsigned short* qrow =
      Qb + ((long)b * SEQ + n0 + (lane & 15)) * 1024 + (lane >> 4) * 8;
  short8 qf[32];
#pragma unroll
  for (int ks = 0; ks < 32; ks++) qf[ks] = *(const short8*)(qrow + ks * 32);
  float* attB = att + (long)b * SEQ * SEQ;
  int ctlo = nt - 16, cthi = nt + 16;
  for (int ct = ctlo + wid; ct <= cthi; ct += 4) {
    if (ct < 0 || ct > (SEQ / 16 - 1)) continue;
    floatx4 acc = (floatx4){0.f, 0.f, 0.f, 0.f};
    const unsigned short* krow =
        Kb + ((long)b * SEQ + ct * 16 + (lane & 15)) * 1024 + (lane >> 4) * 8;
#pragma unroll
    for (int ks = 0; ks < 32; ks++) {
      short8 kf = *(const short8*)(krow + ks * 32);
      acc = __builtin_amdgcn_mfma_f32_16x16x32_bf16(qf[ks], kf, acc, 0, 0, 0);
    }
    int colj = ct * 16 + (lane & 15);
    int rowi = n0 + (lane >> 4) * 4;
#pragma unroll
    for (int r = 0; r < 4; r++)
      attB[(long)(rowi + r) * SEQ + colj] = acc[r];
  }
}

// ---------------- softmax over band + zero fill + band-compact att^T (bf16) ----------------
// attT[b][nt][n&15][mi] = att[b][m = nt*16-256+mi][n],  544 mi slots per row
__global__ __launch_bounds__(256) void softmax_band(
    float* __restrict__ att, unsigned short* __restrict__ attT) {
  __shared__ float red[4];
  long brow = blockIdx.x;
  int b = (int)(brow >> 12);
  int r = (int)(brow & 4095);
  float* row = att + brow * (long)SEQ;
  int lo = r - 255; if (lo < 0) lo = 0;
  int hi = r + 255; if (hi > SEQ - 1) hi = SEQ - 1;
  int t = threadIdx.x, lane = t & 63, wid = t >> 6;

  float m = -1e30f;
  for (int c = lo + t; c <= hi; c += 256) m = fmaxf(m, row[c]);
#pragma unroll
  for (int off = 32; off; off >>= 1) m = fmaxf(m, __shfl_down(m, off, 64));
  if (lane == 0) red[wid] = m;
  __syncthreads();
  m = fmaxf(fmaxf(red[0], red[1]), fmaxf(red[2], red[3]));
  __syncthreads();

  float s = 0.f;
  for (int c = lo + t; c <= hi; c += 256) s += __expf(row[c] - m);
#pragma unroll
  for (int off = 32; off; off >>= 1) s += __shfl_down(s, off, 64);
  if (lane == 0) red[wid] = s;
  __syncthreads();
  float inv = 1.0f / (red[0] + red[1] + red[2] + red[3]);

  for (int c0 = t * 4; c0 < SEQ; c0 += 1024) {
    float4 w;
    float* wp = (float*)&w;
#pragma unroll
    for (int j = 0; j < 4; j++) {
      int c = c0 + j;
      float val = 0.f;
      if (c >= lo && c <= hi) {
        val = __expf(row[c] - m) * inv;
        int ntc = c >> 4;
        int mi = r - ntc * 16 + 256;
        attT[(((long)b * 256 + ntc) * 16 + (c & 15)) * 544 + mi] = f2bf(val);
      }
      wp[j] = val;
    }
    *(float4*)(row + c0) = w;
  }
}

// ---------------- y[b][n][o] = sum_m att[b][m][n] * V[b][m][o]  (banded) ----------------
__global__ __launch_bounds__(256) void attv(
    const unsigned short* __restrict__ attT, const unsigned short* __restrict__ Vt,
    unsigned short* __restrict__ yb) {
  int b = blockIdx.z;
  int nt = blockIdx.x;
  int wid = threadIdx.x >> 6, lane = threadIdx.x & 63;
  int o0 = blockIdx.y * 64 + wid * 16;
  const unsigned short* aBase =
      attT + (((long)b * 256 + nt) * 16 + (lane & 15)) * 544 + (lane >> 4) * 8;
  const unsigned short* vRow = Vt + ((long)b * 1024 + o0 + (lane & 15)) * (long)SEQ;
  int koff = (lane >> 4) * 8;
  int m0 = nt * 16 - 256;
  floatx4 acc = (floatx4){0.f, 0.f, 0.f, 0.f};
  for (int ch = 0; ch < 17; ch++) {
    int m = m0 + ch * 32;
    if (m + 32 <= 0 || m >= SEQ) continue;
    short8 af = *(const short8*)(aBase + ch * 32);
    short8 vf;
    if (m >= 0 && m + 32 <= SEQ) {
      vf = *(const short8*)(vRow + m + koff);
    } else {
#pragma unroll
      for (int j = 0; j < 8; j++) {
        int mm = m + koff + j;
        vf[j] = (mm >= 0 && mm < SEQ) ? (short)vRow[mm] : (short)0;
      }
    }
    acc = __builtin_amdgcn_mfma_f32_16x16x32_bf16(af, vf, acc, 0, 0, 0);
  }
  int nrow = nt * 16 + (lane >> 4) * 4;
  int ocol = o0 + (lane & 15);
#pragma unroll
  for (int r = 0; r < 4; r++)
    yb[((long)b * SEQ + nrow + r) * 1024 + ocol] = f2bf(acc[r]);
}

extern "C" void kernel_launch(void* const* d_in, const int* in_sizes, int n_in,
                              void* d_out, int out_size, void* d_ws, size_t ws_size,
                              hipStream_t stream) {
  const float* x  = (const float*)d_in[0];
  const float* Wk = (const float*)d_in[1];
  const float* Wq = (const float*)d_in[2];
  const float* Wv = (const float*)d_in[3];
  const float* Wo = (const float*)d_in[4];
  float* outY = (float*)d_out;
  float* outAtt = outY + (long)NB * SEQ * DM;  // y first, att second

  char* ws = (char*)d_ws;
  unsigned short* xb  = (unsigned short*)(ws + 0);            // 32 MiB (reused as yb)
  unsigned short* Kb  = (unsigned short*)(ws + 33554432);     // 32 MiB (reused as attT)
  unsigned short* Qb  = (unsigned short*)(ws + 67108864);     // 32 MiB
  unsigned short* Vb  = (unsigned short*)(ws + 100663296);    // 32 MiB
  unsigned short* Vt  = (unsigned short*)(ws + 134217728);    // 32 MiB
  unsigned short* Wkb = (unsigned short*)(ws + 167772160);    // 2 MiB each
  unsigned short* Wqb = Wkb + 1048576;
  unsigned short* Wvb = Wqb + 1048576;
  unsigned short* Wob = Wvb + 1048576;
  unsigned short* attT = Kb;  // alias: Kb dead after attn_logits
  unsigned short* yb = xb;    // alias: xb dead after QKV GEMMs

  cvt_bf16<<<8192, 256, 0, stream>>>(x, xb, NB * SEQ * DM);
  cvt_bf16<<<512, 256, 0, stream>>>(Wk, Wkb, DM * DM);
  cvt_bf16<<<512, 256, 0, stream>>>(Wq, Wqb, DM * DM);
  cvt_bf16<<<512, 256, 0, stream>>>(Wv, Wvb, DM * DM);
  cvt_bf16<<<512, 256, 0, stream>>>(Wo, Wob, DM * DM);

  dim3 gg(128, 8);
  gemm_bt<true><<<gg, 256, 0, stream>>>(xb, Wkb, Kb, 1.0f);
  gemm_bt<true><<<gg, 256, 0, stream>>>(xb, Wqb, Qb, QSCALE);
  gemm_bt<true><<<gg, 256, 0, stream>>>(xb, Wvb, Vb, 1.0f);

  transpose_v<<<dim3(64, 16, NB), 256, 0, stream>>>(Vb, Vt);
  attn_logits<<<dim3(256, NB), 256, 0, stream>>>(Qb, Kb, outAtt);
  hipMemsetAsync(attT, 0, (size_t)NB * 256 * 16 * 544 * 2, stream);
  softmax_band<<<NB * SEQ, 256, 0, stream>>>(outAtt, attT);
  attv<<<dim3(256, 16, NB), 256, 0, stream>>>(attT, Vt, yb);
  gemm_bt<false><<<gg, 256, 0, stream>>>(yb, Wob, outY, 1.0f);
}

// Round 2
// 944.958 us; speedup vs baseline: 1.1797x; 1.1797x over previous
//
#include <hip/hip_runtime.h>
#include <stdint.h>

#define SEQ 4096
#define DM  1024
#define NB  4
#define QSCALE 0.06f

typedef __attribute__((ext_vector_type(8))) short short8;
typedef __attribute__((ext_vector_type(4))) float floatx4;

__device__ __forceinline__ unsigned short f2bf(float f) {
  union { float f; unsigned int u; } v; v.f = f;
  unsigned int u = v.u;
  u += 0x7FFFu + ((u >> 16) & 1u);
  return (unsigned short)(u >> 16);
}

__device__ __forceinline__ void async16(const void* g, void* l) {
  __builtin_amdgcn_global_load_lds(
      (const __attribute__((address_space(1))) void*)g,
      (__attribute__((address_space(3))) void*)l, 16, 0, 0);
}

// ---------------- fp32 -> bf16 convert (8 elems/thread) ----------------
__global__ void cvt_bf16(const float* __restrict__ in,
                         unsigned short* __restrict__ out, int n) {
  int i = (blockIdx.x * 256 + threadIdx.x) * 8;
  if (i >= n) return;
  const float4* p = (const float4*)(in + i);
  float4 a = p[0], b = p[1];
  short8 o;
  o[0] = (short)f2bf(a.x); o[1] = (short)f2bf(a.y);
  o[2] = (short)f2bf(a.z); o[3] = (short)f2bf(a.w);
  o[4] = (short)f2bf(b.x); o[5] = (short)f2bf(b.y);
  o[6] = (short)f2bf(b.z); o[7] = (short)f2bf(b.w);
  *(short8*)(out + i) = o;
}

// ---------------- m97-style 128x128 bf16 GEMM, C = A * W^T ----------------
// A: [M x 1024] bf16 row-major.  W: [Ncols x 1024] bf16 row-major (K-contig).
// C row stride = ldc (elements).
template <bool OUT_BF16>
__global__ __launch_bounds__(256) void gemm_bt(
    const unsigned short* __restrict__ A, const unsigned short* __restrict__ W,
    void* __restrict__ Cout, float alpha, long ldc) {
  __shared__ unsigned short sA[128 * 32];
  __shared__ unsigned short sB[128 * 32];
  const int K = 1024;
  int tid = threadIdx.x;
  int wid = tid >> 6, lane = tid & 63;
  int wr = wid >> 1, wc = wid & 1;
  long rowBase = (long)blockIdx.x * 128;
  int colBase = blockIdx.y * 128;

  floatx4 acc[4][4];
#pragma unroll
  for (int i = 0; i < 4; i++)
#pragma unroll
    for (int j = 0; j < 4; j++) acc[i][j] = (floatx4){0.f, 0.f, 0.f, 0.f};

  int c0 = wid * 64 + lane;
  int c1 = c0 + 256;
  const unsigned short* Ag0 = A + (rowBase + (c0 >> 2)) * K + (c0 & 3) * 8;
  const unsigned short* Ag1 = A + (rowBase + (c1 >> 2)) * K + (c1 & 3) * 8;
  const unsigned short* Bg0 = W + ((long)colBase + (c0 >> 2)) * K + (c0 & 3) * 8;
  const unsigned short* Bg1 = W + ((long)colBase + (c1 >> 2)) * K + (c1 & 3) * 8;
  unsigned short* sA0 = sA + (wid * 64) * 8;
  unsigned short* sA1 = sA + (256 + wid * 64) * 8;
  unsigned short* sB0 = sB + (wid * 64) * 8;
  unsigned short* sB1 = sB + (256 + wid * 64) * 8;

  int aRd = (wr * 64 + (lane & 15)) * 32 + (lane >> 4) * 8;
  int bRd = (wc * 64 + (lane & 15)) * 32 + (lane >> 4) * 8;

  for (int ks = 0; ks < K; ks += 32) {
    async16(Ag0 + ks, sA0);
    async16(Ag1 + ks, sA1);
    async16(Bg0 + ks, sB0);
    async16(Bg1 + ks, sB1);
    __syncthreads();
    short8 af[4], bf[4];
#pragma unroll
    for (int mt = 0; mt < 4; mt++) af[mt] = *(const short8*)(sA + aRd + mt * 512);
#pragma unroll
    for (int nt = 0; nt < 4; nt++) bf[nt] = *(const short8*)(sB + bRd + nt * 512);
#pragma unroll
    for (int mt = 0; mt < 4; mt++)
#pragma unroll
      for (int nt = 0; nt < 4; nt++)
        acc[mt][nt] = __builtin_amdgcn_mfma_f32_16x16x32_bf16(
            af[mt], bf[nt], acc[mt][nt], 0, 0, 0);
    __syncthreads();
  }

  long crow = rowBase + wr * 64 + (lane >> 4) * 4;
  int ccol = colBase + wc * 64 + (lane & 15);
#pragma unroll
  for (int mt = 0; mt < 4; mt++)
#pragma unroll
    for (int nt = 0; nt < 4; nt++)
#pragma unroll
      for (int r = 0; r < 4; r++) {
        float v = acc[mt][nt][r] * alpha;
        long idx = (crow + mt * 16 + r) * ldc + ccol + nt * 16;
        if (OUT_BF16)
          ((unsigned short*)Cout)[idx] = f2bf(v);
        else
          ((float*)Cout)[idx] = v;
      }
}

// ---------------- banded logits: att[b][n][m] = Q[n].K[m], 128x128 tiles ----------------
// grid: (5 col-tiles, 32 row-tiles, NB)
__global__ __launch_bounds__(256) void attn_logits(
    const unsigned short* __restrict__ Qb, const unsigned short* __restrict__ Kb,
    float* __restrict__ att) {
  int b = blockIdx.z;
  int n0 = blockIdx.y * 128;
  int m0 = n0 - 256 + blockIdx.x * 128;
  if (m0 + 128 <= 0 || m0 >= SEQ) return;
  __shared__ unsigned short sA[128 * 32];
  __shared__ unsigned short sB[128 * 32];
  const int K = 1024;
  int tid = threadIdx.x;
  int wid = tid >> 6, lane = tid & 63;
  int wr = wid >> 1, wc = wid & 1;

  floatx4 acc[4][4];
#pragma unroll
  for (int i = 0; i < 4; i++)
#pragma unroll
    for (int j = 0; j < 4; j++) acc[i][j] = (floatx4){0.f, 0.f, 0.f, 0.f};

  int c0 = wid * 64 + lane;
  int c1 = c0 + 256;
  const unsigned short* Qbase = Qb + (long)b * SEQ * K;
  const unsigned short* Kbase = Kb + (long)b * SEQ * K;
  // clamp K row indices at band edges (masked in epilogue)
  int br0 = m0 + (c0 >> 2); br0 = br0 < 0 ? 0 : (br0 > SEQ - 1 ? SEQ - 1 : br0);
  int br1 = m0 + (c1 >> 2); br1 = br1 < 0 ? 0 : (br1 > SEQ - 1 ? SEQ - 1 : br1);
  const unsigned short* Ag0 = Qbase + (long)(n0 + (c0 >> 2)) * K + (c0 & 3) * 8;
  const unsigned short* Ag1 = Qbase + (long)(n0 + (c1 >> 2)) * K + (c1 & 3) * 8;
  const unsigned short* Bg0 = Kbase + (long)br0 * K + (c0 & 3) * 8;
  const unsigned short* Bg1 = Kbase + (long)br1 * K + (c1 & 3) * 8;
  unsigned short* sA0 = sA + (wid * 64) * 8;
  unsigned short* sA1 = sA + (256 + wid * 64) * 8;
  unsigned short* sB0 = sB + (wid * 64) * 8;
  unsigned short* sB1 = sB + (256 + wid * 64) * 8;

  int aRd = (wr * 64 + (lane & 15)) * 32 + (lane >> 4) * 8;
  int bRd = (wc * 64 + (lane & 15)) * 32 + (lane >> 4) * 8;

  for (int ks = 0; ks < K; ks += 32) {
    async16(Ag0 + ks, sA0);
    async16(Ag1 + ks, sA1);
    async16(Bg0 + ks, sB0);
    async16(Bg1 + ks, sB1);
    __syncthreads();
    short8 af[4], bf[4];
#pragma unroll
    for (int mt = 0; mt < 4; mt++) af[mt] = *(const short8*)(sA + aRd + mt * 512);
#pragma unroll
    for (int nt = 0; nt < 4; nt++) bf[nt] = *(const short8*)(sB + bRd + nt * 512);
#pragma unroll
    for (int mt = 0; mt < 4; mt++)
#pragma unroll
      for (int nt = 0; nt < 4; nt++)
        acc[mt][nt] = __builtin_amdgcn_mfma_f32_16x16x32_bf16(
            af[mt], bf[nt], acc[mt][nt], 0, 0, 0);
    __syncthreads();
  }

  float* attB = att + (long)b * SEQ * SEQ;
  int crow = n0 + wr * 64 + (lane >> 4) * 4;
  int ccol = m0 + wc * 64 + (lane & 15);
#pragma unroll
  for (int mt = 0; mt < 4; mt++)
#pragma unroll
    for (int nt = 0; nt < 4; nt++)
#pragma unroll
      for (int r = 0; r < 4; r++) {
        int row = crow + mt * 16 + r;
        int col = ccol + nt * 16;
        int d = row - col;
        if (col >= 0 && col < SEQ && d < 256 && d > -256)
          attB[(long)row * SEQ + col] = acc[mt][nt][r];
      }
}

// ---------------- softmax over band + zero fill + band-compact att^T (bf16) ----------------
// attT[b][nt][n&15][mi] = att[b][m = nt*16-256+mi][n],  544 mi slots per row
__global__ __launch_bounds__(256) void softmax_band(
    float* __restrict__ att, unsigned short* __restrict__ attT) {
  __shared__ float red[4];
  long brow = blockIdx.x;
  int b = (int)(brow >> 12);
  int r = (int)(brow & 4095);
  float* row = att + brow * (long)SEQ;
  int lo = r - 255; if (lo < 0) lo = 0;
  int hi = r + 255; if (hi > SEQ - 1) hi = SEQ - 1;
  int t = threadIdx.x, lane = t & 63, wid = t >> 6;

  float m = -1e30f;
  for (int c = lo + t; c <= hi; c += 256) m = fmaxf(m, row[c]);
#pragma unroll
  for (int off = 32; off; off >>= 1) m = fmaxf(m, __shfl_down(m, off, 64));
  if (lane == 0) red[wid] = m;
  __syncthreads();
  m = fmaxf(fmaxf(red[0], red[1]), fmaxf(red[2], red[3]));
  __syncthreads();

  float s = 0.f;
  for (int c = lo + t; c <= hi; c += 256) s += __expf(row[c] - m);
#pragma unroll
  for (int off = 32; off; off >>= 1) s += __shfl_down(s, off, 64);
  if (lane == 0) red[wid] = s;
  __syncthreads();
  float inv = 1.0f / (red[0] + red[1] + red[2] + red[3]);

  for (int c0 = t * 4; c0 < SEQ; c0 += 1024) {
    float4 w;
    float* wp = (float*)&w;
#pragma unroll
    for (int j = 0; j < 4; j++) {
      int c = c0 + j;
      float val = 0.f;
      if (c >= lo && c <= hi) {
        val = __expf(row[c] - m) * inv;
        int ntc = c >> 4;
        int mi = r - ntc * 16 + 256;
        attT[(((long)b * 256 + ntc) * 16 + (c & 15)) * 544 + mi] = f2bf(val);
      }
      wp[j] = val;
    }
    *(float4*)(row + c0) = w;
  }
}

// ---------------- y[b][n][o] = sum_m att[b][m][n] * V[b][m][o]  (banded) ----------------
// Vt layout: Vt[o][b*SEQ + m]  (from gemm_bt(Wv, x))
__global__ __launch_bounds__(256) void attv(
    const unsigned short* __restrict__ attT, const unsigned short* __restrict__ Vt,
    unsigned short* __restrict__ yb) {
  int b = blockIdx.z;
  int nt = blockIdx.x;
  int wid = threadIdx.x >> 6, lane = threadIdx.x & 63;
  int o0 = blockIdx.y * 64 + wid * 16;
  const unsigned short* aBase =
      attT + (((long)b * 256 + nt) * 16 + (lane & 15)) * 544 + (lane >> 4) * 8;
  const unsigned short* vRow =
      Vt + (long)(o0 + (lane & 15)) * (NB * SEQ) + (long)b * SEQ;
  int koff = (lane >> 4) * 8;
  int m0 = nt * 16 - 256;
  floatx4 acc = (floatx4){0.f, 0.f, 0.f, 0.f};
  for (int ch = 0; ch < 17; ch++) {
    int m = m0 + ch * 32;
    if (m + 32 <= 0 || m >= SEQ) continue;
    short8 af = *(const short8*)(aBase + ch * 32);
    short8 vf;
    if (m >= 0 && m + 32 <= SEQ) {
      vf = *(const short8*)(vRow + m + koff);
    } else {
#pragma unroll
      for (int j = 0; j < 8; j++) {
        int mm = m + koff + j;
        vf[j] = (mm >= 0 && mm < SEQ) ? (short)vRow[mm] : (short)0;
      }
    }
    acc = __builtin_amdgcn_mfma_f32_16x16x32_bf16(af, vf, acc, 0, 0, 0);
  }
  int nrow = nt * 16 + (lane >> 4) * 4;
  int ocol = o0 + (lane & 15);
#pragma unroll
  for (int r = 0; r < 4; r++)
    yb[((long)b * SEQ + nrow + r) * 1024 + ocol] = f2bf(acc[r]);
}

extern "C" void kernel_launch(void* const* d_in, const int* in_sizes, int n_in,
                              void* d_out, int out_size, void* d_ws, size_t ws_size,
                              hipStream_t stream) {
  const float* x  = (const float*)d_in[0];
  const float* Wk = (const float*)d_in[1];
  const float* Wq = (const float*)d_in[2];
  const float* Wv = (const float*)d_in[3];
  const float* Wo = (const float*)d_in[4];
  float* outY = (float*)d_out;
  float* outAtt = outY + (long)NB * SEQ * DM;  // y first, att second

  char* ws = (char*)d_ws;
  unsigned short* xb  = (unsigned short*)(ws + 0);            // 32 MiB (reused as yb)
  unsigned short* Kb  = (unsigned short*)(ws + 33554432);     // 32 MiB (reused as attT)
  unsigned short* Qb  = (unsigned short*)(ws + 67108864);     // 32 MiB
  unsigned short* Vt  = (unsigned short*)(ws + 100663296);    // 32 MiB  Vt[o][b*SEQ+m]
  unsigned short* Wkb = (unsigned short*)(ws + 134217728);    // 2 MiB each
  unsigned short* Wqb = Wkb + 1048576;
  unsigned short* Wvb = Wqb + 1048576;
  unsigned short* Wob = Wvb + 1048576;
  unsigned short* attT = Kb;  // alias: Kb dead after attn_logits
  unsigned short* yb = xb;    // alias: xb dead after Q/K/Vt GEMMs

  cvt_bf16<<<8192, 256, 0, stream>>>(x, xb, NB * SEQ * DM);
  cvt_bf16<<<512, 256, 0, stream>>>(Wk, Wkb, DM * DM);
  cvt_bf16<<<512, 256, 0, stream>>>(Wq, Wqb, DM * DM);
  cvt_bf16<<<512, 256, 0, stream>>>(Wv, Wvb, DM * DM);
  cvt_bf16<<<512, 256, 0, stream>>>(Wo, Wob, DM * DM);

  dim3 gg(128, 8);
  gemm_bt<true><<<gg, 256, 0, stream>>>(xb, Wkb, Kb, 1.0f, 1024);
  gemm_bt<true><<<gg, 256, 0, stream>>>(xb, Wqb, Qb, QSCALE, 1024);
  // Vt = Wv * x^T : C[o][b*4096+m], ldc = 16384
  gemm_bt<true><<<dim3(8, 128), 256, 0, stream>>>(Wvb, xb, Vt, 1.0f, NB * SEQ);

  attn_logits<<<dim3(5, 32, NB), 256, 0, stream>>>(Qb, Kb, outAtt);
  hipMemsetAsync(attT, 0, (size_t)NB * 256 * 16 * 544 * 2, stream);
  softmax_band<<<NB * SEQ, 256, 0, stream>>>(outAtt, attT);
  attv<<<dim3(256, 16, NB), 256, 0, stream>>>(attT, Vt, yb);
  gemm_bt<false><<<gg, 256, 0, stream>>>(yb, Wob, outY, 1.0f, 1024);
}

// Round 3
// 875.244 us; speedup vs baseline: 1.2736x; 1.0797x over previous
//
#include <hip/hip_runtime.h>
#include <stdint.h>

#define SEQ 4096
#define DM  1024
#define NB  4
#define QSCALE 0.06f

typedef __attribute__((ext_vector_type(8))) short short8;
typedef __attribute__((ext_vector_type(4))) float floatx4;

__device__ __forceinline__ unsigned short f2bf(float f) {
  union { float f; unsigned int u; } v; v.f = f;
  unsigned int u = v.u;
  u += 0x7FFFu + ((u >> 16) & 1u);
  return (unsigned short)(u >> 16);
}

__device__ __forceinline__ void async16(const void* g, void* l) {
  __builtin_amdgcn_global_load_lds(
      (const __attribute__((address_space(1))) void*)g,
      (__attribute__((address_space(3))) void*)l, 16, 0, 0);
}

// ---------------- fp32 -> bf16 convert (8 elems/thread) ----------------
__global__ void cvt_bf16(const float* __restrict__ in,
                         unsigned short* __restrict__ out, int n) {
  int i = (blockIdx.x * 256 + threadIdx.x) * 8;
  if (i >= n) return;
  const float4* p = (const float4*)(in + i);
  float4 a = p[0], b = p[1];
  short8 o;
  o[0] = (short)f2bf(a.x); o[1] = (short)f2bf(a.y);
  o[2] = (short)f2bf(a.z); o[3] = (short)f2bf(a.w);
  o[4] = (short)f2bf(b.x); o[5] = (short)f2bf(b.y);
  o[6] = (short)f2bf(b.z); o[7] = (short)f2bf(b.w);
  *(short8*)(out + i) = o;
}

// ---------------- m97-style 128x128 bf16 GEMM, C = A * W^T ----------------
template <bool OUT_BF16>
__global__ __launch_bounds__(256) void gemm_bt(
    const unsigned short* __restrict__ A, const unsigned short* __restrict__ W,
    void* __restrict__ Cout, float alpha, long ldc) {
  __shared__ unsigned short sA[128 * 32];
  __shared__ unsigned short sB[128 * 32];
  const int K = 1024;
  int tid = threadIdx.x;
  int wid = tid >> 6, lane = tid & 63;
  int wr = wid >> 1, wc = wid & 1;
  long rowBase = (long)blockIdx.x * 128;
  int colBase = blockIdx.y * 128;

  floatx4 acc[4][4];
#pragma unroll
  for (int i = 0; i < 4; i++)
#pragma unroll
    for (int j = 0; j < 4; j++) acc[i][j] = (floatx4){0.f, 0.f, 0.f, 0.f};

  int c0 = wid * 64 + lane;
  int c1 = c0 + 256;
  const unsigned short* Ag0 = A + (rowBase + (c0 >> 2)) * K + (c0 & 3) * 8;
  const unsigned short* Ag1 = A + (rowBase + (c1 >> 2)) * K + (c1 & 3) * 8;
  const unsigned short* Bg0 = W + ((long)colBase + (c0 >> 2)) * K + (c0 & 3) * 8;
  const unsigned short* Bg1 = W + ((long)colBase + (c1 >> 2)) * K + (c1 & 3) * 8;
  unsigned short* sA0 = sA + (wid * 64) * 8;
  unsigned short* sA1 = sA + (256 + wid * 64) * 8;
  unsigned short* sB0 = sB + (wid * 64) * 8;
  unsigned short* sB1 = sB + (256 + wid * 64) * 8;

  int aRd = (wr * 64 + (lane & 15)) * 32 + (lane >> 4) * 8;
  int bRd = (wc * 64 + (lane & 15)) * 32 + (lane >> 4) * 8;

  for (int ks = 0; ks < K; ks += 32) {
    async16(Ag0 + ks, sA0);
    async16(Ag1 + ks, sA1);
    async16(Bg0 + ks, sB0);
    async16(Bg1 + ks, sB1);
    __syncthreads();
    short8 af[4], bf[4];
#pragma unroll
    for (int mt = 0; mt < 4; mt++) af[mt] = *(const short8*)(sA + aRd + mt * 512);
#pragma unroll
    for (int nt = 0; nt < 4; nt++) bf[nt] = *(const short8*)(sB + bRd + nt * 512);
#pragma unroll
    for (int mt = 0; mt < 4; mt++)
#pragma unroll
      for (int nt = 0; nt < 4; nt++)
        acc[mt][nt] = __builtin_amdgcn_mfma_f32_16x16x32_bf16(
            af[mt], bf[nt], acc[mt][nt], 0, 0, 0);
    __syncthreads();
  }

  long crow = rowBase + wr * 64 + (lane >> 4) * 4;
  int ccol = colBase + wc * 64 + (lane & 15);
#pragma unroll
  for (int mt = 0; mt < 4; mt++)
#pragma unroll
    for (int nt = 0; nt < 4; nt++)
#pragma unroll
      for (int r = 0; r < 4; r++) {
        float v = acc[mt][nt][r] * alpha;
        long idx = (crow + mt * 16 + r) * ldc + ccol + nt * 16;
        if (OUT_BF16)
          ((unsigned short*)Cout)[idx] = f2bf(v);
        else
          ((float*)Cout)[idx] = v;
      }
}

// ---------------- banded logits: att[b][n][m] = Q[n].K[m], 128x128 tiles ----------------
__global__ __launch_bounds__(256) void attn_logits(
    const unsigned short* __restrict__ Qb, const unsigned short* __restrict__ Kb,
    float* __restrict__ att) {
  int b = blockIdx.z;
  int n0 = blockIdx.y * 128;
  int m0 = n0 - 256 + blockIdx.x * 128;
  if (m0 + 128 <= 0 || m0 >= SEQ) return;
  __shared__ unsigned short sA[128 * 32];
  __shared__ unsigned short sB[128 * 32];
  const int K = 1024;
  int tid = threadIdx.x;
  int wid = tid >> 6, lane = tid & 63;
  int wr = wid >> 1, wc = wid & 1;

  floatx4 acc[4][4];
#pragma unroll
  for (int i = 0; i < 4; i++)
#pragma unroll
    for (int j = 0; j < 4; j++) acc[i][j] = (floatx4){0.f, 0.f, 0.f, 0.f};

  int c0 = wid * 64 + lane;
  int c1 = c0 + 256;
  const unsigned short* Qbase = Qb + (long)b * SEQ * K;
  const unsigned short* Kbase = Kb + (long)b * SEQ * K;
  int br0 = m0 + (c0 >> 2); br0 = br0 < 0 ? 0 : (br0 > SEQ - 1 ? SEQ - 1 : br0);
  int br1 = m0 + (c1 >> 2); br1 = br1 < 0 ? 0 : (br1 > SEQ - 1 ? SEQ - 1 : br1);
  const unsigned short* Ag0 = Qbase + (long)(n0 + (c0 >> 2)) * K + (c0 & 3) * 8;
  const unsigned short* Ag1 = Qbase + (long)(n0 + (c1 >> 2)) * K + (c1 & 3) * 8;
  const unsigned short* Bg0 = Kbase + (long)br0 * K + (c0 & 3) * 8;
  const unsigned short* Bg1 = Kbase + (long)br1 * K + (c1 & 3) * 8;
  unsigned short* sA0 = sA + (wid * 64) * 8;
  unsigned short* sA1 = sA + (256 + wid * 64) * 8;
  unsigned short* sB0 = sB + (wid * 64) * 8;
  unsigned short* sB1 = sB + (256 + wid * 64) * 8;

  int aRd = (wr * 64 + (lane & 15)) * 32 + (lane >> 4) * 8;
  int bRd = (wc * 64 + (lane & 15)) * 32 + (lane >> 4) * 8;

  for (int ks = 0; ks < K; ks += 32) {
    async16(Ag0 + ks, sA0);
    async16(Ag1 + ks, sA1);
    async16(Bg0 + ks, sB0);
    async16(Bg1 + ks, sB1);
    __syncthreads();
    short8 af[4], bf[4];
#pragma unroll
    for (int mt = 0; mt < 4; mt++) af[mt] = *(const short8*)(sA + aRd + mt * 512);
#pragma unroll
    for (int nt = 0; nt < 4; nt++) bf[nt] = *(const short8*)(sB + bRd + nt * 512);
#pragma unroll
    for (int mt = 0; mt < 4; mt++)
#pragma unroll
      for (int nt = 0; nt < 4; nt++)
        acc[mt][nt] = __builtin_amdgcn_mfma_f32_16x16x32_bf16(
            af[mt], bf[nt], acc[mt][nt], 0, 0, 0);
    __syncthreads();
  }

  float* attB = att + (long)b * SEQ * SEQ;
  int crow = n0 + wr * 64 + (lane >> 4) * 4;
  int ccol = m0 + wc * 64 + (lane & 15);
#pragma unroll
  for (int mt = 0; mt < 4; mt++)
#pragma unroll
    for (int nt = 0; nt < 4; nt++)
#pragma unroll
      for (int r = 0; r < 4; r++) {
        int row = crow + mt * 16 + r;
        int col = ccol + nt * 16;
        int d = row - col;
        if (col >= 0 && col < SEQ && d < 256 && d > -256)
          attB[(long)row * SEQ + col] = acc[mt][nt][r];
      }
}

// ---------------- softmax over band, 16 rows/block, LDS band cache ----------------
// attT[b][nt][n&15][mi] = att[b][m = nt*16-256+mi][n] (bf16), coalesced 32B runs
__global__ __launch_bounds__(256) void softmax_band(
    float* __restrict__ att, unsigned short* __restrict__ attT) {
  __shared__ float e_lds[16 * 545];
  __shared__ float inv_s[16];
  int blk = blockIdx.x;          // 1024 blocks: 4 batches x 256 row-groups
  int b = blk >> 8;
  int r0 = (blk & 255) * 16;
  int tid = threadIdx.x;
  int row = tid >> 4;            // 0..15 within block
  int t16 = tid & 15;
  int i = r0 + row;
  int jbase = r0 - 272;
  float* arow = att + ((long)b * SEQ + i) * (long)SEQ;

  // phase 1a: load band window into regs, row max
  float raw[34];
  float m = -1e30f;
#pragma unroll
  for (int s = 0; s < 34; s++) {
    int jj = s * 16 + t16;
    int j = jbase + jj;
    bool ok = (j >= 0) && (j < SEQ) && (j >= i - 255) && (j <= i + 255);
    float v = ok ? arow[j] : -1e30f;
    raw[s] = v;
    m = fmaxf(m, v);
  }
#pragma unroll
  for (int off = 8; off; off >>= 1) m = fmaxf(m, __shfl_xor(m, off, 16));

  // phase 1b: exp, store to LDS, row sum
  float sum = 0.f;
#pragma unroll
  for (int s = 0; s < 34; s++) {
    int jj = s * 16 + t16;
    float e = (raw[s] > -1e29f) ? __expf(raw[s] - m) : 0.f;
    e_lds[row * 545 + jj] = e;
    sum += e;
  }
#pragma unroll
  for (int off = 8; off; off >>= 1) sum += __shfl_xor(sum, off, 16);
  float invr = 1.0f / sum;
  if (t16 == 0) inv_s[row] = invr;
  __syncthreads();

  // phase 1c: write full fp32 row (zeros outside band)
  for (int s = 0; s < 64; s++) {
    int j0 = (s * 16 + t16) * 4;
    float4 w;
    float* wp = (float*)&w;
#pragma unroll
    for (int k = 0; k < 4; k++) {
      int j = j0 + k;
      bool ok = (j >= i - 255) && (j <= i + 255);
      int jj = j - jbase;
      jj = jj < 0 ? 0 : (jj > 543 ? 543 : jj);
      wp[k] = ok ? e_lds[row * 545 + jj] * invr : 0.f;
    }
    *(float4*)(arow + j0) = w;
  }

  // phase 2: write attT tiles, thread -> (n = tid>>4, mi offset = tid&15)
  int n = tid >> 4;
  int mi16 = tid & 15;
  int i2 = r0 + mi16;
  float inv2 = inv_s[mi16];
  int nt0 = (r0 >> 4) - 16, nt1 = (r0 >> 4) + 16;
  for (int nt = nt0; nt <= nt1; nt++) {
    if (nt < 0 || nt > 255) continue;
    int j = nt * 16 + n;
    bool ok = (j >= i2 - 255) && (j <= i2 + 255);
    int jj = j - jbase;  // in [16, 543] for valid nt
    float val = ok ? e_lds[mi16 * 545 + jj] * inv2 : 0.f;
    int mi = i2 - nt * 16 + 256;
    attT[(((long)b * 256 + nt) * 16 + n) * 544 + mi] = f2bf(val);
  }
}

// ---------------- y[b][n][o] = sum_m att[b][m][n] * V[b][m][o]  (banded) ----------------
// Vt layout: Vt[o][b*SEQ + m]
__global__ __launch_bounds__(256) void attv(
    const unsigned short* __restrict__ attT, const unsigned short* __restrict__ Vt,
    unsigned short* __restrict__ yb) {
  int b = blockIdx.z;
  int nt = blockIdx.x;
  int wid = threadIdx.x >> 6, lane = threadIdx.x & 63;
  int o0 = blockIdx.y * 64 + wid * 16;
  const unsigned short* aBase =
      attT + (((long)b * 256 + nt) * 16 + (lane & 15)) * 544 + (lane >> 4) * 8;
  const unsigned short* vRow =
      Vt + (long)(o0 + (lane & 15)) * (NB * SEQ) + (long)b * SEQ;
  int koff = (lane >> 4) * 8;
  int m0 = nt * 16 - 256;
  floatx4 acc = (floatx4){0.f, 0.f, 0.f, 0.f};
  for (int ch = 0; ch < 17; ch++) {
    int m = m0 + ch * 32;
    if (m + 32 <= 0 || m >= SEQ) continue;
    short8 af = *(const short8*)(aBase + ch * 32);
    short8 vf;
    if (m >= 0 && m + 32 <= SEQ) {
      vf = *(const short8*)(vRow + m + koff);
    } else {
#pragma unroll
      for (int j = 0; j < 8; j++) {
        int mm = m + koff + j;
        vf[j] = (mm >= 0 && mm < SEQ) ? (short)vRow[mm] : (short)0;
      }
    }
    acc = __builtin_amdgcn_mfma_f32_16x16x32_bf16(af, vf, acc, 0, 0, 0);
  }
  int nrow = nt * 16 + (lane >> 4) * 4;
  int ocol = o0 + (lane & 15);
#pragma unroll
  for (int r = 0; r < 4; r++)
    yb[((long)b * SEQ + nrow + r) * 1024 + ocol] = f2bf(acc[r]);
}

extern "C" void kernel_launch(void* const* d_in, const int* in_sizes, int n_in,
                              void* d_out, int out_size, void* d_ws, size_t ws_size,
                              hipStream_t stream) {
  const float* x  = (const float*)d_in[0];
  const float* Wk = (const float*)d_in[1];
  const float* Wq = (const float*)d_in[2];
  const float* Wv = (const float*)d_in[3];
  const float* Wo = (const float*)d_in[4];
  float* outY = (float*)d_out;
  float* outAtt = outY + (long)NB * SEQ * DM;

  char* ws = (char*)d_ws;
  unsigned short* xb  = (unsigned short*)(ws + 0);            // 32 MiB (reused as yb)
  unsigned short* Kb  = (unsigned short*)(ws + 33554432);     // 32 MiB (reused as attT)
  unsigned short* Qb  = (unsigned short*)(ws + 67108864);     // 32 MiB
  unsigned short* Vt  = (unsigned short*)(ws + 100663296);    // 32 MiB  Vt[o][b*SEQ+m]
  unsigned short* Wkb = (unsigned short*)(ws + 134217728);
  unsigned short* Wqb = Wkb + 1048576;
  unsigned short* Wvb = Wqb + 1048576;
  unsigned short* Wob = Wvb + 1048576;
  unsigned short* attT = Kb;  // alias: Kb dead after attn_logits
  unsigned short* yb = xb;    // alias: xb dead after Q/K/Vt GEMMs

  cvt_bf16<<<8192, 256, 0, stream>>>(x, xb, NB * SEQ * DM);
  cvt_bf16<<<512, 256, 0, stream>>>(Wk, Wkb, DM * DM);
  cvt_bf16<<<512, 256, 0, stream>>>(Wq, Wqb, DM * DM);
  cvt_bf16<<<512, 256, 0, stream>>>(Wv, Wvb, DM * DM);
  cvt_bf16<<<512, 256, 0, stream>>>(Wo, Wob, DM * DM);

  dim3 gg(128, 8);
  gemm_bt<true><<<gg, 256, 0, stream>>>(xb, Wkb, Kb, 1.0f, 1024);
  gemm_bt<true><<<gg, 256, 0, stream>>>(xb, Wqb, Qb, QSCALE, 1024);
  gemm_bt<true><<<dim3(8, 128), 256, 0, stream>>>(Wvb, xb, Vt, 1.0f, NB * SEQ);

  attn_logits<<<dim3(5, 32, NB), 256, 0, stream>>>(Qb, Kb, outAtt);
  hipMemsetAsync(attT, 0, (size_t)NB * 256 * 16 * 544 * 2, stream);
  softmax_band<<<1024, 256, 0, stream>>>(outAtt, attT);
  attv<<<dim3(256, 16, NB), 256, 0, stream>>>(attT, Vt, yb);
  gemm_bt<false><<<gg, 256, 0, stream>>>(yb, Wob, outY, 1.0f, 1024);
}

// Round 4
// 730.810 us; speedup vs baseline: 1.5254x; 1.1976x over previous
//
#include <hip/hip_runtime.h>
#include <stdint.h>

#define SEQ 4096
#define DM  1024
#define NB  4
#define QSCALE 0.06f

typedef __attribute__((ext_vector_type(8))) short short8;
typedef __attribute__((ext_vector_type(4))) float floatx4;

__device__ __forceinline__ unsigned short f2bf(float f) {
  union { float f; unsigned int u; } v; v.f = f;
  unsigned int u = v.u;
  u += 0x7FFFu + ((u >> 16) & 1u);
  return (unsigned short)(u >> 16);
}

__device__ __forceinline__ void async16(const void* g, void* l) {
  __builtin_amdgcn_global_load_lds(
      (const __attribute__((address_space(1))) void*)g,
      (__attribute__((address_space(3))) void*)l, 16, 0, 0);
}

// ---------------- fp32 -> bf16 convert (8 elems/thread) ----------------
__global__ void cvt_bf16(const float* __restrict__ in,
                         unsigned short* __restrict__ out, int n) {
  int i = (blockIdx.x * 256 + threadIdx.x) * 8;
  if (i >= n) return;
  const float4* p = (const float4*)(in + i);
  float4 a = p[0], b = p[1];
  short8 o;
  o[0] = (short)f2bf(a.x); o[1] = (short)f2bf(a.y);
  o[2] = (short)f2bf(a.z); o[3] = (short)f2bf(a.w);
  o[4] = (short)f2bf(b.x); o[5] = (short)f2bf(b.y);
  o[6] = (short)f2bf(b.z); o[7] = (short)f2bf(b.w);
  *(short8*)(out + i) = o;
}

// ---------------- m97-style 128x128 bf16 GEMM, C = A * W^T ----------------
template <bool OUT_BF16>
__global__ __launch_bounds__(256) void gemm_bt(
    const unsigned short* __restrict__ A, const unsigned short* __restrict__ W,
    void* __restrict__ Cout, float alpha, long ldc) {
  __shared__ unsigned short sA[128 * 32];
  __shared__ unsigned short sB[128 * 32];
  const int K = 1024;
  int tid = threadIdx.x;
  int wid = tid >> 6, lane = tid & 63;
  int wr = wid >> 1, wc = wid & 1;
  long rowBase = (long)blockIdx.x * 128;
  int colBase = blockIdx.y * 128;

  floatx4 acc[4][4];
#pragma unroll
  for (int i = 0; i < 4; i++)
#pragma unroll
    for (int j = 0; j < 4; j++) acc[i][j] = (floatx4){0.f, 0.f, 0.f, 0.f};

  int c0 = wid * 64 + lane;
  int c1 = c0 + 256;
  const unsigned short* Ag0 = A + (rowBase + (c0 >> 2)) * K + (c0 & 3) * 8;
  const unsigned short* Ag1 = A + (rowBase + (c1 >> 2)) * K + (c1 & 3) * 8;
  const unsigned short* Bg0 = W + ((long)colBase + (c0 >> 2)) * K + (c0 & 3) * 8;
  const unsigned short* Bg1 = W + ((long)colBase + (c1 >> 2)) * K + (c1 & 3) * 8;
  unsigned short* sA0 = sA + (wid * 64) * 8;
  unsigned short* sA1 = sA + (256 + wid * 64) * 8;
  unsigned short* sB0 = sB + (wid * 64) * 8;
  unsigned short* sB1 = sB + (256 + wid * 64) * 8;

  int aRd = (wr * 64 + (lane & 15)) * 32 + (lane >> 4) * 8;
  int bRd = (wc * 64 + (lane & 15)) * 32 + (lane >> 4) * 8;

  for (int ks = 0; ks < K; ks += 32) {
    async16(Ag0 + ks, sA0);
    async16(Ag1 + ks, sA1);
    async16(Bg0 + ks, sB0);
    async16(Bg1 + ks, sB1);
    __syncthreads();
    short8 af[4], bf[4];
#pragma unroll
    for (int mt = 0; mt < 4; mt++) af[mt] = *(const short8*)(sA + aRd + mt * 512);
#pragma unroll
    for (int nt = 0; nt < 4; nt++) bf[nt] = *(const short8*)(sB + bRd + nt * 512);
#pragma unroll
    for (int mt = 0; mt < 4; mt++)
#pragma unroll
      for (int nt = 0; nt < 4; nt++)
        acc[mt][nt] = __builtin_amdgcn_mfma_f32_16x16x32_bf16(
            af[mt], bf[nt], acc[mt][nt], 0, 0, 0);
    __syncthreads();
  }

  long crow = rowBase + wr * 64 + (lane >> 4) * 4;
  int ccol = colBase + wc * 64 + (lane & 15);
#pragma unroll
  for (int mt = 0; mt < 4; mt++)
#pragma unroll
    for (int nt = 0; nt < 4; nt++)
#pragma unroll
      for (int r = 0; r < 4; r++) {
        float v = acc[mt][nt][r] * alpha;
        long idx = (crow + mt * 16 + r) * ldc + ccol + nt * 16;
        if (OUT_BF16)
          ((unsigned short*)Cout)[idx] = f2bf(v);
        else
          ((float*)Cout)[idx] = v;
      }
}

// ---------------- banded logits: att[b][n][m] = Q[n].K[m], 128x128 tiles ----------------
__global__ __launch_bounds__(256) void attn_logits(
    const unsigned short* __restrict__ Qb, const unsigned short* __restrict__ Kb,
    float* __restrict__ att) {
  int b = blockIdx.z;
  int n0 = blockIdx.y * 128;
  int m0 = n0 - 256 + blockIdx.x * 128;
  if (m0 + 128 <= 0 || m0 >= SEQ) return;
  __shared__ unsigned short sA[128 * 32];
  __shared__ unsigned short sB[128 * 32];
  const int K = 1024;
  int tid = threadIdx.x;
  int wid = tid >> 6, lane = tid & 63;
  int wr = wid >> 1, wc = wid & 1;

  floatx4 acc[4][4];
#pragma unroll
  for (int i = 0; i < 4; i++)
#pragma unroll
    for (int j = 0; j < 4; j++) acc[i][j] = (floatx4){0.f, 0.f, 0.f, 0.f};

  int c0 = wid * 64 + lane;
  int c1 = c0 + 256;
  const unsigned short* Qbase = Qb + (long)b * SEQ * K;
  const unsigned short* Kbase = Kb + (long)b * SEQ * K;
  int br0 = m0 + (c0 >> 2); br0 = br0 < 0 ? 0 : (br0 > SEQ - 1 ? SEQ - 1 : br0);
  int br1 = m0 + (c1 >> 2); br1 = br1 < 0 ? 0 : (br1 > SEQ - 1 ? SEQ - 1 : br1);
  const unsigned short* Ag0 = Qbase + (long)(n0 + (c0 >> 2)) * K + (c0 & 3) * 8;
  const unsigned short* Ag1 = Qbase + (long)(n0 + (c1 >> 2)) * K + (c1 & 3) * 8;
  const unsigned short* Bg0 = Kbase + (long)br0 * K + (c0 & 3) * 8;
  const unsigned short* Bg1 = Kbase + (long)br1 * K + (c1 & 3) * 8;
  unsigned short* sA0 = sA + (wid * 64) * 8;
  unsigned short* sA1 = sA + (256 + wid * 64) * 8;
  unsigned short* sB0 = sB + (wid * 64) * 8;
  unsigned short* sB1 = sB + (256 + wid * 64) * 8;

  int aRd = (wr * 64 + (lane & 15)) * 32 + (lane >> 4) * 8;
  int bRd = (wc * 64 + (lane & 15)) * 32 + (lane >> 4) * 8;

  for (int ks = 0; ks < K; ks += 32) {
    async16(Ag0 + ks, sA0);
    async16(Ag1 + ks, sA1);
    async16(Bg0 + ks, sB0);
    async16(Bg1 + ks, sB1);
    __syncthreads();
    short8 af[4], bf[4];
#pragma unroll
    for (int mt = 0; mt < 4; mt++) af[mt] = *(const short8*)(sA + aRd + mt * 512);
#pragma unroll
    for (int nt = 0; nt < 4; nt++) bf[nt] = *(const short8*)(sB + bRd + nt * 512);
#pragma unroll
    for (int mt = 0; mt < 4; mt++)
#pragma unroll
      for (int nt = 0; nt < 4; nt++)
        acc[mt][nt] = __builtin_amdgcn_mfma_f32_16x16x32_bf16(
            af[mt], bf[nt], acc[mt][nt], 0, 0, 0);
    __syncthreads();
  }

  float* attB = att + (long)b * SEQ * SEQ;
  int crow = n0 + wr * 64 + (lane >> 4) * 4;
  int ccol = m0 + wc * 64 + (lane & 15);
#pragma unroll
  for (int mt = 0; mt < 4; mt++)
#pragma unroll
    for (int nt = 0; nt < 4; nt++)
#pragma unroll
      for (int r = 0; r < 4; r++) {
        int row = crow + mt * 16 + r;
        int col = ccol + nt * 16;
        int d = row - col;
        if (col >= 0 && col < SEQ && d < 256 && d > -256)
          attB[(long)row * SEQ + col] = acc[mt][nt][r];
      }
}

// ---------------- softmax over band, 16 rows/block, LDS band cache ----------------
// attT2[b][nb][n&127][mi] = att[b][m = (nb*128)-256+mi][n], 640 mi slots
__global__ __launch_bounds__(256) void softmax_band(
    float* __restrict__ att, unsigned short* __restrict__ attT2) {
  __shared__ float e_lds[16 * 545];
  __shared__ float inv_s[16];
  int blk = blockIdx.x;          // 1024 blocks: 4 batches x 256 row-groups
  int b = blk >> 8;
  int r0 = (blk & 255) * 16;
  int tid = threadIdx.x;
  int row = tid >> 4;            // 0..15 within block
  int t16 = tid & 15;
  int i = r0 + row;
  int jbase = r0 - 272;
  float* arow = att + ((long)b * SEQ + i) * (long)SEQ;

  // phase 1a: load band window into regs, row max
  float raw[34];
  float m = -1e30f;
#pragma unroll
  for (int s = 0; s < 34; s++) {
    int jj = s * 16 + t16;
    int j = jbase + jj;
    bool ok = (j >= 0) && (j < SEQ) && (j >= i - 255) && (j <= i + 255);
    float v = ok ? arow[j] : -1e30f;
    raw[s] = v;
    m = fmaxf(m, v);
  }
#pragma unroll
  for (int off = 8; off; off >>= 1) m = fmaxf(m, __shfl_xor(m, off, 16));

  // phase 1b: exp, store to LDS, row sum
  float sum = 0.f;
#pragma unroll
  for (int s = 0; s < 34; s++) {
    int jj = s * 16 + t16;
    float e = (raw[s] > -1e29f) ? __expf(raw[s] - m) : 0.f;
    e_lds[row * 545 + jj] = e;
    sum += e;
  }
#pragma unroll
  for (int off = 8; off; off >>= 1) sum += __shfl_xor(sum, off, 16);
  float invr = 1.0f / sum;
  if (t16 == 0) inv_s[row] = invr;
  __syncthreads();

  // phase 1c: write full fp32 row (zeros outside band)
  for (int s = 0; s < 64; s++) {
    int j0 = (s * 16 + t16) * 4;
    float4 w;
    float* wp = (float*)&w;
#pragma unroll
    for (int k = 0; k < 4; k++) {
      int j = j0 + k;
      bool ok = (j >= i - 255) && (j <= i + 255);
      int jj = j - jbase;
      jj = jj < 0 ? 0 : (jj > 543 ? 543 : jj);
      wp[k] = ok ? e_lds[row * 545 + jj] * invr : 0.f;
    }
    *(float4*)(arow + j0) = w;
  }

  // phase 2: write attT2 (128-aligned band-compact transpose)
  // thread: mi16 = tid&15 -> our m-row i2; nn = tid>>4 -> n stride 16
  int nn = tid >> 4;
  int mi16 = tid & 15;
  int i2 = r0 + mi16;
  float inv2 = inv_s[mi16];
  for (int s = 0; s <= 32; s++) {
    int n = r0 - 256 + s * 16 + nn;
    if (n < 0 || n >= SEQ) continue;
    int N0b = n & ~127;
    int mi = i2 - N0b + 256;
    if (mi < 0 || mi >= 640) continue;
    bool ok = (n >= i2 - 255) && (n <= i2 + 255);
    int jj = n - jbase;  // in [16, 543]
    float val = ok ? e_lds[mi16 * 545 + jj] * inv2 : 0.f;
    attT2[(((long)b * 32 + (N0b >> 7)) * 128 + (n & 127)) * 640 + mi] = f2bf(val);
  }
}

// ---------------- y[b][n][o] = sum_m att[b][m][n] * V[b][m][o] as 128x128 GEMM ----------------
// A = attT2[b][nb][128 n][640 mi], B = Vt[o][b*SEQ+m] (m contiguous), K=640
__global__ __launch_bounds__(256) void attv_gemm(
    const unsigned short* __restrict__ attT2, const unsigned short* __restrict__ Vt,
    unsigned short* __restrict__ yb) {
  __shared__ unsigned short sA[128 * 32];
  __shared__ unsigned short sB[128 * 32];
  const int KA = 640;
  int b = blockIdx.z;
  int tid = threadIdx.x;
  int wid = tid >> 6, lane = tid & 63;
  int wr = wid >> 1, wc = wid & 1;
  int N0 = blockIdx.x * 128;
  int o0 = blockIdx.y * 128;

  floatx4 acc[4][4];
#pragma unroll
  for (int i = 0; i < 4; i++)
#pragma unroll
    for (int j = 0; j < 4; j++) acc[i][j] = (floatx4){0.f, 0.f, 0.f, 0.f};

  int c0 = wid * 64 + lane;
  int c1 = c0 + 256;
  const unsigned short* Abase =
      attT2 + (((long)b * 32 + blockIdx.x) * 128) * KA;
  const unsigned short* Ag0 = Abase + (long)(c0 >> 2) * KA + (c0 & 3) * 8;
  const unsigned short* Ag1 = Abase + (long)(c1 >> 2) * KA + (c1 & 3) * 8;
  const unsigned short* Bg0 = Vt + (long)(o0 + (c0 >> 2)) * (NB * SEQ) + (c0 & 3) * 8;
  const unsigned short* Bg1 = Vt + (long)(o0 + (c1 >> 2)) * (NB * SEQ) + (c1 & 3) * 8;
  unsigned short* sA0 = sA + (wid * 64) * 8;
  unsigned short* sA1 = sA + (256 + wid * 64) * 8;
  unsigned short* sB0 = sB + (wid * 64) * 8;
  unsigned short* sB1 = sB + (256 + wid * 64) * 8;

  int aRd = (wr * 64 + (lane & 15)) * 32 + (lane >> 4) * 8;
  int bRd = (wc * 64 + (lane & 15)) * 32 + (lane >> 4) * 8;

  for (int ks = 0; ks < KA; ks += 32) {
    // m chunk for this k-step (whole chunk in- or out-of-bounds; clamp is safe
    // because A is zero on OOB-m slots)
    int mg = N0 - 256 + ks;
    int mc = mg < 0 ? 0 : (mg > SEQ - 32 ? SEQ - 32 : mg);
    long boff = (long)b * SEQ + mc;
    async16(Ag0 + ks, sA0);
    async16(Ag1 + ks, sA1);
    async16(Bg0 + boff, sB0);
    async16(Bg1 + boff, sB1);
    __syncthreads();
    short8 af[4], bf[4];
#pragma unroll
    for (int mt = 0; mt < 4; mt++) af[mt] = *(const short8*)(sA + aRd + mt * 512);
#pragma unroll
    for (int nt = 0; nt < 4; nt++) bf[nt] = *(const short8*)(sB + bRd + nt * 512);
#pragma unroll
    for (int mt = 0; mt < 4; mt++)
#pragma unroll
      for (int nt = 0; nt < 4; nt++)
        acc[mt][nt] = __builtin_amdgcn_mfma_f32_16x16x32_bf16(
            af[mt], bf[nt], acc[mt][nt], 0, 0, 0);
    __syncthreads();
  }

  long crow = (long)b * SEQ + N0 + wr * 64 + (lane >> 4) * 4;
  int ccol = o0 + wc * 64 + (lane & 15);
#pragma unroll
  for (int mt = 0; mt < 4; mt++)
#pragma unroll
    for (int nt = 0; nt < 4; nt++)
#pragma unroll
      for (int r = 0; r < 4; r++)
        yb[(crow + mt * 16 + r) * DM + ccol + nt * 16] = f2bf(acc[mt][nt][r]);
}

extern "C" void kernel_launch(void* const* d_in, const int* in_sizes, int n_in,
                              void* d_out, int out_size, void* d_ws, size_t ws_size,
                              hipStream_t stream) {
  const float* x  = (const float*)d_in[0];
  const float* Wk = (const float*)d_in[1];
  const float* Wq = (const float*)d_in[2];
  const float* Wv = (const float*)d_in[3];
  const float* Wo = (const float*)d_in[4];
  float* outY = (float*)d_out;
  float* outAtt = outY + (long)NB * SEQ * DM;

  char* ws = (char*)d_ws;
  unsigned short* xb  = (unsigned short*)(ws + 0);            // 32 MiB (reused as yb)
  unsigned short* Kb  = (unsigned short*)(ws + 33554432);     // 32 MiB (reused as attT2)
  unsigned short* Qb  = (unsigned short*)(ws + 67108864);     // 32 MiB
  unsigned short* Vt  = (unsigned short*)(ws + 100663296);    // 32 MiB  Vt[o][b*SEQ+m]
  unsigned short* Wkb = (unsigned short*)(ws + 134217728);
  unsigned short* Wqb = Wkb + 1048576;
  unsigned short* Wvb = Wqb + 1048576;
  unsigned short* Wob = Wvb + 1048576;
  unsigned short* attT2 = Kb;  // alias: Kb dead after attn_logits (21 MB)
  unsigned short* yb = xb;     // alias: xb dead after Q/K/Vt GEMMs

  cvt_bf16<<<8192, 256, 0, stream>>>(x, xb, NB * SEQ * DM);
  cvt_bf16<<<512, 256, 0, stream>>>(Wk, Wkb, DM * DM);
  cvt_bf16<<<512, 256, 0, stream>>>(Wq, Wqb, DM * DM);
  cvt_bf16<<<512, 256, 0, stream>>>(Wv, Wvb, DM * DM);
  cvt_bf16<<<512, 256, 0, stream>>>(Wo, Wob, DM * DM);

  dim3 gg(128, 8);
  gemm_bt<true><<<gg, 256, 0, stream>>>(xb, Wkb, Kb, 1.0f, 1024);
  gemm_bt<true><<<gg, 256, 0, stream>>>(xb, Wqb, Qb, QSCALE, 1024);
  gemm_bt<true><<<dim3(8, 128), 256, 0, stream>>>(Wvb, xb, Vt, 1.0f, NB * SEQ);

  attn_logits<<<dim3(5, 32, NB), 256, 0, stream>>>(Qb, Kb, outAtt);
  hipMemsetAsync(attT2, 0, (size_t)NB * 32 * 128 * 640 * 2, stream);
  softmax_band<<<1024, 256, 0, stream>>>(outAtt, attT2);
  attv_gemm<<<dim3(32, 8, NB), 256, 0, stream>>>(attT2, Vt, yb);
  gemm_bt<false><<<gg, 256, 0, stream>>>(yb, Wob, outY, 1.0f, 1024);
}